// Round 2
// baseline (371.824 us; speedup 1.0000x reference)
//
#include <hip/hip_runtime.h>
#include <hip/hip_bf16.h>
#include <stdint.h>

#define B_ 2
#define S_ 1024
#define H_ 16
#define D_ 128
#define HID 2048
#define POS_ 1024
#define L_ 2048
#define NQKV 6144

using f32x4  = __attribute__((ext_vector_type(4))) float;
using bf16x8 = __attribute__((ext_vector_type(8))) short;
using us4    = __attribute__((ext_vector_type(4))) unsigned short;

typedef const __attribute__((address_space(1))) void* gp_t;
typedef __attribute__((address_space(3))) void* lp_t;

__device__ __forceinline__ unsigned short f2bf(float f){
  union { float f; uint32_t u; } v; v.f = f;
  uint32_t r = v.u + 0x7FFFu + ((v.u >> 16) & 1u);
  return (unsigned short)(r >> 16);
}

__global__ void k_cvt(const float* __restrict__ s, unsigned short* __restrict__ d, int n){
  int i = (blockIdx.x * blockDim.x + threadIdx.x) * 4;
  if (i < n){
    float4 v = *(const float4*)(s + i);
    us4 o;
    o[0] = f2bf(v.x); o[1] = f2bf(v.y); o[2] = f2bf(v.z); o[3] = f2bf(v.w);
    *(us4*)(d + i) = o;
  }
}

__global__ void k_cache(const float* __restrict__ kc, const float* __restrict__ vc,
                        unsigned short* __restrict__ kf, unsigned short* __restrict__ vf){
  int i = (blockIdx.x * blockDim.x + threadIdx.x) * 4;
  if (i >= B_*POS_*H_*D_) return;
  int b = i >> 21;
  int rem = i & ((1 << 21) - 1);
  size_t src = (size_t)b * (2*POS_*H_*D_) + rem;   // layer 0 slice
  size_t dst = (size_t)b * (L_*H_*D_) + rem;       // first POS_ rows of k_full
  float4 k4 = *(const float4*)(kc + src);
  float4 v4 = *(const float4*)(vc + src);
  us4 ko, vo;
  ko[0]=f2bf(k4.x); ko[1]=f2bf(k4.y); ko[2]=f2bf(k4.z); ko[3]=f2bf(k4.w);
  vo[0]=f2bf(v4.x); vo[1]=f2bf(v4.y); vo[2]=f2bf(v4.z); vo[3]=f2bf(v4.w);
  *(us4*)(kf + dst) = ko;
  *(us4*)(vf + dst) = vo;
}

__global__ void k_rope(const float* __restrict__ qkv, const float* __restrict__ cosb,
    const float* __restrict__ sinb, float* __restrict__ kout, float* __restrict__ vout,
    unsigned short* __restrict__ qb, unsigned short* __restrict__ kf, unsigned short* __restrict__ vf)
{
  int idx = blockIdx.x*blockDim.x + threadIdx.x;  // B*S*H*64 = 2^21 threads
  int j  = idx & 63;
  int hh = (idx >> 6) & 15;
  int s  = (idx >> 10) & 1023;
  int b  = idx >> 20;
  int m  = b*S_ + s;
  float c  = cosb[(POS_ + s)*64 + j];
  float sn = sinb[(POS_ + s)*64 + j];
  size_t base = (size_t)m*NQKV + hh*D_ + j;
  float q1 = qkv[base],          q2 = qkv[base + 64];
  float k1 = qkv[base + HID],    k2 = qkv[base + HID + 64];
  float v1 = qkv[base + 2*HID],  v2 = qkv[base + 2*HID + 64];
  float qr = c*q1 - sn*q2, qi = sn*q1 + c*q2;
  float kr = c*k1 - sn*k2, ki = sn*k1 + c*k2;
  size_t o = (size_t)m*HID + hh*D_ + j;
  kout[o] = kr; kout[o + 64] = ki;
  vout[o] = v1; vout[o + 64] = v2;
  qb[o] = f2bf(qr); qb[o + 64] = f2bf(qi);
  size_t fo = ((size_t)(b*L_ + POS_ + s)*H_ + hh)*D_ + j;
  kf[fo] = f2bf(kr); kf[fo + 64] = f2bf(ki);
  vf[fo] = f2bf(v1); vf[fo + 64] = f2bf(v2);
}

// C[m][n] = sum_k A[m][k]*B[n][k] + bias[n];  A: Md x Kd bf16, B: Nd x Kd bf16 (i.e. B^T layout)
__global__ __launch_bounds__(256) void k_gemm(const unsigned short* __restrict__ A,
    const unsigned short* __restrict__ Bm, const float* __restrict__ bias,
    float* __restrict__ C, int Md, int Nd, int Kd)
{
  __shared__ unsigned short As[128*64];
  __shared__ unsigned short Bs[128*64];
  const int tid = threadIdx.x;
  const int lane = tid & 63, w = tid >> 6;
  const int wr = w >> 1, wc = w & 1;
  const int lg = lane >> 4, lr = lane & 15;
  const int tiles_n = Nd >> 7;
  const int tm = blockIdx.x / tiles_n, tn = blockIdx.x % tiles_n;
  f32x4 acc[4][4];
  #pragma unroll
  for (int i=0;i<4;++i)
    #pragma unroll
    for (int j=0;j<4;++j){ f32x4 z = {0.f,0.f,0.f,0.f}; acc[i][j] = z; }

  for (int k0 = 0; k0 < Kd; k0 += 64){
    // stage 128x64 bf16 A-tile and B-tile, XOR-swizzled via pre-swizzled global source
    #pragma unroll
    for (int j=0;j<4;++j){
      int chunk = j*256 + w*64 + lane;     // 1024 chunks of 16B, 8 chunks/row
      int row = chunk >> 3, cc = chunk & 7;
      int ccs = cc ^ (row & 7);
      const unsigned short* ga = A  + (size_t)(tm*128 + row)*Kd + k0 + ccs*8;
      __builtin_amdgcn_global_load_lds((gp_t)ga,
          (lp_t)((char*)As + (j*256 + w*64)*16), 16, 0, 0);
      const unsigned short* gb = Bm + (size_t)(tn*128 + row)*Kd + k0 + ccs*8;
      __builtin_amdgcn_global_load_lds((gp_t)gb,
          (lp_t)((char*)Bs + (j*256 + w*64)*16), 16, 0, 0);
    }
    __syncthreads();
    #pragma unroll
    for (int ks=0; ks<2; ++ks){
      bf16x8 af[4], bf[4];
      #pragma unroll
      for (int mi=0;mi<4;++mi){
        int row = wr*64 + mi*16 + lr;
        int byte = (row*128 + ks*64 + lg*16) ^ ((row & 7) << 4);
        af[mi] = *(const bf16x8*)((const char*)As + byte);
      }
      #pragma unroll
      for (int ni=0;ni<4;++ni){
        int row = wc*64 + ni*16 + lr;
        int byte = (row*128 + ks*64 + lg*16) ^ ((row & 7) << 4);
        bf[ni] = *(const bf16x8*)((const char*)Bs + byte);
      }
      #pragma unroll
      for (int mi=0;mi<4;++mi)
        #pragma unroll
        for (int ni=0;ni<4;++ni)
          acc[mi][ni] = __builtin_amdgcn_mfma_f32_16x16x32_bf16(af[mi], bf[ni], acc[mi][ni], 0, 0, 0);
    }
    __syncthreads();
  }
  #pragma unroll
  for (int mi=0;mi<4;++mi)
    #pragma unroll
    for (int ni=0;ni<4;++ni){
      int col = tn*128 + wc*64 + ni*16 + lr;
      float bv = bias[col];
      #pragma unroll
      for (int i=0;i<4;++i){
        int row = tm*128 + wr*64 + mi*16 + lg*4 + i;
        C[(size_t)row*Nd + col] = acc[mi][ni][i] + bv;
      }
    }
}

__global__ __launch_bounds__(256) void k_attn(const unsigned short* __restrict__ Q,
    const unsigned short* __restrict__ Kf, const unsigned short* __restrict__ Vf,
    const float* __restrict__ mask, unsigned short* __restrict__ Ob)
{
  __shared__ unsigned short Kt[64*128];     // K tile, swizzled
  __shared__ unsigned short Vt[128*72];     // V tile transposed, padded stride 72
  __shared__ unsigned short Pw[4][16*64];   // per-wave P tile, swizzled
  const int tid = threadIdx.x;
  const int lane = tid & 63, w = tid >> 6;
  const int lg = lane >> 4, lr = lane & 15;
  const int bid = blockIdx.x;
  const int qblk = bid & 15, h = (bid >> 4) & 15, b = bid >> 8;
  const int q0 = qblk * 64;

  bf16x8 qf[4];
  {
    const unsigned short* qbase = Q + ((size_t)(b*S_ + q0 + w*16 + lr))*HID + h*D_;
    #pragma unroll
    for (int ks=0; ks<4; ++ks)
      qf[ks] = *(const bf16x8*)(qbase + ks*32 + lg*8);
  }
  f32x4 oacc[8];
  #pragma unroll
  for (int i=0;i<8;++i){ f32x4 z = {0.f,0.f,0.f,0.f}; oacc[i] = z; }
  float m_i[4] = {-1e30f,-1e30f,-1e30f,-1e30f};
  float l_i[4] = {0.f,0.f,0.f,0.f};
  const float isc = 0.08838834764831845f;   // 1/sqrt(128)

  for (int t0 = 0; t0 < L_; t0 += 64){
    // stage K tile [64][128] via global_load_lds, pre-swizzled source
    #pragma unroll
    for (int j=0;j<4;++j){
      int chunk = j*256 + w*64 + lane;      // 16 chunks/row
      int row = chunk >> 4, cc = chunk & 15;
      int ccs = cc ^ (row & 7);
      const unsigned short* g = Kf + ((size_t)(b*L_ + t0 + row)*H_ + h)*D_ + ccs*8;
      __builtin_amdgcn_global_load_lds((gp_t)g,
          (lp_t)((char*)Kt + (j*256 + w*64)*16), 16, 0, 0);
    }
    // stage V transposed: Vt[d][t], stride 72
    {
      int tt = tid >> 4, d0 = (tid & 15) * 8;
      #pragma unroll
      for (int rep=0; rep<4; ++rep){
        int t = tt + rep*16;
        uint4 vv = *(const uint4*)(Vf + ((size_t)(b*L_ + t0 + t)*H_ + h)*D_ + d0);
        const unsigned short* pv = (const unsigned short*)&vv;
        #pragma unroll
        for (int e=0;e<8;++e) Vt[(d0+e)*72 + t] = pv[e];
      }
    }
    __syncthreads();

    // scores: S = Q K^T (per wave: 16 q-rows x 64 t-cols)
    f32x4 sc[4];
    #pragma unroll
    for (int nf=0;nf<4;++nf){
      f32x4 a = {0.f,0.f,0.f,0.f};
      #pragma unroll
      for (int ks=0;ks<4;++ks){
        int row = nf*16 + lr;
        int byte = (row*256 + ks*64 + lg*16) ^ ((row & 7) << 4);
        bf16x8 kb = *(const bf16x8*)((const char*)Kt + byte);
        a = __builtin_amdgcn_mfma_f32_16x16x32_bf16(qf[ks], kb, a, 0, 0, 0);
      }
      sc[nf] = a;
    }

    // NOTE: reference tiles mask as concatenate([mask]*H, axis=0) over score
    // rows (B*H): mask batch index = (b*H + h) % B = h & 1 (B=2, H even).
    const float* mb = mask + (size_t)(h & 1)*L_*L_ + (size_t)(POS_ + q0 + w*16)*L_ + t0;
    float sv[4][4];
    float tmax[4] = {-1e30f,-1e30f,-1e30f,-1e30f};
    #pragma unroll
    for (int nf=0;nf<4;++nf)
      #pragma unroll
      for (int i=0;i<4;++i){
        float v = sc[nf][i]*isc + mb[(size_t)(lg*4+i)*L_ + nf*16 + lr];
        sv[nf][i] = v;
        tmax[i] = fmaxf(tmax[i], v);
      }
    #pragma unroll
    for (int i=0;i<4;++i){
      tmax[i] = fmaxf(tmax[i], __shfl_xor(tmax[i], 1));
      tmax[i] = fmaxf(tmax[i], __shfl_xor(tmax[i], 2));
      tmax[i] = fmaxf(tmax[i], __shfl_xor(tmax[i], 4));
      tmax[i] = fmaxf(tmax[i], __shfl_xor(tmax[i], 8));
    }
    float corr[4];
    #pragma unroll
    for (int i=0;i<4;++i){
      float mn = fmaxf(m_i[i], tmax[i]);
      corr[i] = __expf(m_i[i] - mn);
      m_i[i] = mn;
    }
    float rs[4] = {0.f,0.f,0.f,0.f};
    float pp[4][4];
    #pragma unroll
    for (int nf=0;nf<4;++nf)
      #pragma unroll
      for (int i=0;i<4;++i){
        float p = __expf(sv[nf][i] - m_i[i]);
        pp[nf][i] = p;
        rs[i] += p;
      }
    #pragma unroll
    for (int i=0;i<4;++i){
      rs[i] += __shfl_xor(rs[i], 1);
      rs[i] += __shfl_xor(rs[i], 2);
      rs[i] += __shfl_xor(rs[i], 4);
      rs[i] += __shfl_xor(rs[i], 8);
      l_i[i] = l_i[i]*corr[i] + rs[i];
    }
    #pragma unroll
    for (int df=0;df<8;++df)
      #pragma unroll
      for (int i=0;i<4;++i) oacc[df][i] *= corr[i];

    // P -> per-wave LDS (swizzled), then PV MFMAs
    #pragma unroll
    for (int nf=0;nf<4;++nf)
      #pragma unroll
      for (int i=0;i<4;++i){
        int row = lg*4 + i;
        int byte = (row*128 + nf*32 + lr*2) ^ ((row & 7) << 4);
        *(unsigned short*)((char*)(&Pw[w][0]) + byte) = f2bf(pp[nf][i]);
      }
    __asm__ volatile("s_waitcnt lgkmcnt(0)" ::: "memory");
    #pragma unroll
    for (int ks2=0; ks2<2; ++ks2){
      int pbyte = (lr*128 + ks2*64 + lg*16) ^ ((lr & 7) << 4);
      bf16x8 pa = *(const bf16x8*)((const char*)(&Pw[w][0]) + pbyte);
      #pragma unroll
      for (int df=0;df<8;++df){
        bf16x8 vb = *(const bf16x8*)(&Vt[(df*16+lr)*72 + ks2*32 + lg*8]);
        oacc[df] = __builtin_amdgcn_mfma_f32_16x16x32_bf16(pa, vb, oacc[df], 0, 0, 0);
      }
    }
    __syncthreads();
  }
  size_t ob = ((size_t)(b*S_ + q0 + w*16))*HID + h*D_;
  #pragma unroll
  for (int df=0;df<8;++df)
    #pragma unroll
    for (int i=0;i<4;++i){
      float val = oacc[df][i] / l_i[i];
      Ob[ob + (size_t)(lg*4+i)*HID + df*16 + lr] = f2bf(val);
    }
}

extern "C" void kernel_launch(void* const* d_in, const int* in_sizes, int n_in,
                              void* d_out, int out_size, void* d_ws, size_t ws_size,
                              hipStream_t stream){
  const float* x    = (const float*)d_in[0];
  const float* mask = (const float*)d_in[1];
  const float* cosb = (const float*)d_in[2];
  const float* sinb = (const float*)d_in[3];
  const float* kc   = (const float*)d_in[4];
  const float* vc   = (const float*)d_in[5];
  const float* Wq   = (const float*)d_in[8];
  const float* bq   = (const float*)d_in[9];
  const float* Wk   = (const float*)d_in[10];
  const float* bk   = (const float*)d_in[11];
  const float* Wv   = (const float*)d_in[12];
  const float* bv   = (const float*)d_in[13];
  const float* Wo   = (const float*)d_in[14];
  const float* bo   = (const float*)d_in[15];

  float* out  = (float*)d_out;
  float* kout = out + 4194304;
  float* vout = out + 8388608;

  char* ws = (char*)d_ws;
  float*          qkv   = (float*)(ws);                      // 2048*6144*4  = 50331648
  unsigned short* xb    = (unsigned short*)(ws + 50331648);  // 8388608
  unsigned short* Wqkvb = (unsigned short*)(ws + 58720256);  // 25165824
  unsigned short* Wob   = (unsigned short*)(ws + 83886080);  // 8388608
  float*          bqkv  = (float*)(ws + 92274688);           // 24576
  unsigned short* qb    = (unsigned short*)(ws + 92299264);  // 8388608
  unsigned short* kf    = (unsigned short*)(ws + 100687872); // 16777216
  unsigned short* vf    = (unsigned short*)(ws + 117465088); // 16777216
  unsigned short* attnb = (unsigned short*)(ws + 134242304); // 8388608

  hipMemcpyAsync(bqkv,        bq, 2048*sizeof(float), hipMemcpyDeviceToDevice, stream);
  hipMemcpyAsync(bqkv + 2048, bk, 2048*sizeof(float), hipMemcpyDeviceToDevice, stream);
  hipMemcpyAsync(bqkv + 4096, bv, 2048*sizeof(float), hipMemcpyDeviceToDevice, stream);

  k_cvt<<<4096, 256, 0, stream>>>(x,  xb, 4194304);
  k_cvt<<<4096, 256, 0, stream>>>(Wq, Wqkvb,            4194304);
  k_cvt<<<4096, 256, 0, stream>>>(Wk, Wqkvb + 4194304,  4194304);
  k_cvt<<<4096, 256, 0, stream>>>(Wv, Wqkvb + 8388608,  4194304);
  k_cvt<<<4096, 256, 0, stream>>>(Wo, Wob, 4194304);
  k_cache<<<4096, 256, 0, stream>>>(kc, vc, kf, vf);

  k_gemm<<<16*48, 256, 0, stream>>>(xb, Wqkvb, bqkv, qkv, 2048, 6144, 2048);
  k_rope<<<8192, 256, 0, stream>>>(qkv, cosb, sinb, kout, vout, qb, kf, vf);
  k_attn<<<512, 256, 0, stream>>>(qb, kf, vf, mask, attnb);
  k_gemm<<<16*16, 256, 0, stream>>>(attnb, Wob, bo, out, 2048, 2048, 2048);

  (void)in_sizes; (void)n_in; (void)out_size; (void)ws_size;
}

// Round 3
// 271.029 us; speedup vs baseline: 1.3719x; 1.3719x over previous
//
#include <hip/hip_runtime.h>
#include <hip/hip_bf16.h>
#include <stdint.h>

#define B_ 2
#define S_ 1024
#define H_ 16
#define D_ 128
#define HID 2048
#define POS_ 1024
#define L_ 2048
#define NQKV 6144

using f32x4  = __attribute__((ext_vector_type(4))) float;
using bf16x8 = __attribute__((ext_vector_type(8))) short;
using us4    = __attribute__((ext_vector_type(4))) unsigned short;

typedef const __attribute__((address_space(1))) void* gp_t;
typedef __attribute__((address_space(3))) void* lp_t;

__device__ __forceinline__ unsigned short f2bf(float f){
  union { float f; uint32_t u; } v; v.f = f;
  uint32_t r = v.u + 0x7FFFu + ((v.u >> 16) & 1u);
  return (unsigned short)(r >> 16);
}

__global__ void k_cvt(const float* __restrict__ s, unsigned short* __restrict__ d, int n){
  int i = (blockIdx.x * blockDim.x + threadIdx.x) * 4;
  if (i < n){
    float4 v = *(const float4*)(s + i);
    us4 o;
    o[0] = f2bf(v.x); o[1] = f2bf(v.y); o[2] = f2bf(v.z); o[3] = f2bf(v.w);
    *(us4*)(d + i) = o;
  }
}

__global__ void k_cache(const float* __restrict__ kc, unsigned short* __restrict__ kf){
  int i = (blockIdx.x * blockDim.x + threadIdx.x) * 4;
  if (i >= B_*POS_*H_*D_) return;
  int b = i >> 21;
  int rem = i & ((1 << 21) - 1);
  size_t src = (size_t)b * (2*POS_*H_*D_) + rem;   // layer 0 slice
  size_t dst = (size_t)b * (L_*H_*D_) + rem;       // first POS_ rows of k_full
  float4 k4 = *(const float4*)(kc + src);
  us4 ko;
  ko[0]=f2bf(k4.x); ko[1]=f2bf(k4.y); ko[2]=f2bf(k4.z); ko[3]=f2bf(k4.w);
  *(us4*)(kf + dst) = ko;
}

__global__ void k_rope(const float* __restrict__ qkv, const float* __restrict__ cosb,
    const float* __restrict__ sinb, float* __restrict__ kout, float* __restrict__ vout,
    unsigned short* __restrict__ qb, unsigned short* __restrict__ kf)
{
  int idx = blockIdx.x*blockDim.x + threadIdx.x;  // B*S*H*64 = 2^21 threads
  int j  = idx & 63;
  int hh = (idx >> 6) & 15;
  int s  = (idx >> 10) & 1023;
  int b  = idx >> 20;
  int m  = b*S_ + s;
  float c  = cosb[(POS_ + s)*64 + j];
  float sn = sinb[(POS_ + s)*64 + j];
  size_t base = (size_t)m*NQKV + hh*D_ + j;
  float q1 = qkv[base],          q2 = qkv[base + 64];
  float k1 = qkv[base + HID],    k2 = qkv[base + HID + 64];
  float v1 = qkv[base + 2*HID],  v2 = qkv[base + 2*HID + 64];
  float qr = c*q1 - sn*q2, qi = sn*q1 + c*q2;
  float kr = c*k1 - sn*k2, ki = sn*k1 + c*k2;
  size_t o = (size_t)m*HID + hh*D_ + j;
  kout[o] = kr; kout[o + 64] = ki;
  vout[o] = v1; vout[o + 64] = v2;
  qb[o] = f2bf(qr); qb[o + 64] = f2bf(qi);
  size_t fo = ((size_t)(b*L_ + POS_ + s)*H_ + hh)*D_ + j;
  kf[fo] = f2bf(kr); kf[fo + 64] = f2bf(ki);
}

// Build V^T globally: vt[b][h][d][t], bf16.  t<POS_ from vc fp32; t>=POS_ from qkv (v part).
__global__ __launch_bounds__(256) void k_vtrans(const float* __restrict__ vc,
    const float* __restrict__ qkv, unsigned short* __restrict__ vt)
{
  __shared__ unsigned short T[64*130];
  int blk = blockIdx.x;          // b*512 + h*32 + tt
  int tt = blk & 31, h = (blk >> 5) & 15, b = blk >> 9;
  int t0 = tt * 64;
  int tid = threadIdx.x;
  int d0 = (tid & 31) * 4, tr = tid >> 5;     // 8 rows/pass
  #pragma unroll
  for (int pass=0; pass<8; ++pass){
    int t = tr + pass*8;
    int gt = t0 + t;
    float4 v4;
    if (gt < POS_){
      v4 = *(const float4*)(vc + (((size_t)(b*2*POS_ + gt))*H_ + h)*D_ + d0);
    } else {
      v4 = *(const float4*)(qkv + (size_t)(b*S_ + gt - POS_)*NQKV + 2*HID + h*D_ + d0);
    }
    us4 o; o[0]=f2bf(v4.x); o[1]=f2bf(v4.y); o[2]=f2bf(v4.z); o[3]=f2bf(v4.w);
    *(us4*)(&T[t*130 + d0]) = o;
  }
  __syncthreads();
  int d = tid >> 1, th = (tid & 1) * 32;
  uint4 buf4[4];
  unsigned short* buf = (unsigned short*)buf4;
  #pragma unroll
  for (int e=0;e<32;++e) buf[e] = T[(th+e)*130 + d];
  unsigned short* dst = vt + (((size_t)(b*H_ + h)*D_ + d)*L_) + t0 + th;
  #pragma unroll
  for (int c=0;c<4;++c) *(uint4*)(dst + c*8) = buf4[c];
}

// C[m][n] = sum_k A[m][k]*B[n][k] + bias[n];  A: Md x Kd bf16, B: Nd x Kd bf16 (i.e. B^T layout)
__global__ __launch_bounds__(256) void k_gemm(const unsigned short* __restrict__ A,
    const unsigned short* __restrict__ Bm, const float* __restrict__ bias,
    float* __restrict__ C, int Md, int Nd, int Kd)
{
  __shared__ unsigned short As[128*64];
  __shared__ unsigned short Bs[128*64];
  const int tid = threadIdx.x;
  const int lane = tid & 63, w = tid >> 6;
  const int wr = w >> 1, wc = w & 1;
  const int lg = lane >> 4, lr = lane & 15;
  const int tiles_n = Nd >> 7;
  const int tm = blockIdx.x / tiles_n, tn = blockIdx.x % tiles_n;
  f32x4 acc[4][4];
  #pragma unroll
  for (int i=0;i<4;++i)
    #pragma unroll
    for (int j=0;j<4;++j){ f32x4 z = {0.f,0.f,0.f,0.f}; acc[i][j] = z; }

  for (int k0 = 0; k0 < Kd; k0 += 64){
    #pragma unroll
    for (int j=0;j<4;++j){
      int chunk = j*256 + w*64 + lane;     // 1024 chunks of 16B, 8 chunks/row
      int row = chunk >> 3, cc = chunk & 7;
      int ccs = cc ^ (row & 7);
      const unsigned short* ga = A  + (size_t)(tm*128 + row)*Kd + k0 + ccs*8;
      __builtin_amdgcn_global_load_lds((gp_t)ga,
          (lp_t)((char*)As + (j*256 + w*64)*16), 16, 0, 0);
      const unsigned short* gb = Bm + (size_t)(tn*128 + row)*Kd + k0 + ccs*8;
      __builtin_amdgcn_global_load_lds((gp_t)gb,
          (lp_t)((char*)Bs + (j*256 + w*64)*16), 16, 0, 0);
    }
    __syncthreads();
    #pragma unroll
    for (int ks=0; ks<2; ++ks){
      bf16x8 af[4], bf[4];
      #pragma unroll
      for (int mi=0;mi<4;++mi){
        int row = wr*64 + mi*16 + lr;
        int byte = (row*128 + ks*64 + lg*16) ^ ((row & 7) << 4);
        af[mi] = *(const bf16x8*)((const char*)As + byte);
      }
      #pragma unroll
      for (int ni=0;ni<4;++ni){
        int row = wc*64 + ni*16 + lr;
        int byte = (row*128 + ks*64 + lg*16) ^ ((row & 7) << 4);
        bf[ni] = *(const bf16x8*)((const char*)Bs + byte);
      }
      #pragma unroll
      for (int mi=0;mi<4;++mi)
        #pragma unroll
        for (int ni=0;ni<4;++ni)
          acc[mi][ni] = __builtin_amdgcn_mfma_f32_16x16x32_bf16(af[mi], bf[ni], acc[mi][ni], 0, 0, 0);
    }
    __syncthreads();
  }
  #pragma unroll
  for (int mi=0;mi<4;++mi)
    #pragma unroll
    for (int ni=0;ni<4;++ni){
      int col = tn*128 + wc*64 + ni*16 + lr;
      float bv = bias[col];
      #pragma unroll
      for (int i=0;i<4;++i){
        int row = tm*128 + wr*64 + mi*16 + lg*4 + i;
        C[(size_t)row*Nd + col] = acc[mi][ni][i] + bv;
      }
    }
}

__global__ __launch_bounds__(256) void k_attn(const unsigned short* __restrict__ Q,
    const unsigned short* __restrict__ Kf, const unsigned short* __restrict__ vt,
    const float* __restrict__ mask, unsigned short* __restrict__ Ob)
{
  __shared__ unsigned short Kt[64*128];     // K tile [t][d], swizzled
  __shared__ unsigned short Vt[128*64];     // V^T tile [d][t], swizzled
  __shared__ unsigned short Pw[4][16*64];   // per-wave P tile, swizzled
  const int tid = threadIdx.x;
  const int lane = tid & 63, w = tid >> 6;
  const int lg = lane >> 4, lr = lane & 15;
  const int bid = blockIdx.x;
  const int qblk = bid & 15, h = (bid >> 4) & 15, b = bid >> 8;
  const int q0 = qblk * 64;

  bf16x8 qf[4];
  {
    const unsigned short* qbase = Q + ((size_t)(b*S_ + q0 + w*16 + lr))*HID + h*D_;
    #pragma unroll
    for (int ks=0; ks<4; ++ks)
      qf[ks] = *(const bf16x8*)(qbase + ks*32 + lg*8);
  }
  f32x4 oacc[8];
  #pragma unroll
  for (int i=0;i<8;++i){ f32x4 z = {0.f,0.f,0.f,0.f}; oacc[i] = z; }
  float m_i[4] = {-1e30f,-1e30f,-1e30f,-1e30f};
  float l_i[4] = {0.f,0.f,0.f,0.f};
  const float isc = 0.08838834764831845f;   // 1/sqrt(128)
  const unsigned short* vtb = vt + ((size_t)(b*H_ + h)*D_)*L_;

  for (int t0 = 0; t0 < L_; t0 += 64){
    // stage K tile [64][128] via global_load_lds, pre-swizzled source
    #pragma unroll
    for (int j=0;j<4;++j){
      int chunk = j*256 + w*64 + lane;      // 16 chunks/row
      int row = chunk >> 4, cc = chunk & 15;
      int ccs = cc ^ (row & 7);
      const unsigned short* g = Kf + ((size_t)(b*L_ + t0 + row)*H_ + h)*D_ + ccs*8;
      __builtin_amdgcn_global_load_lds((gp_t)g,
          (lp_t)((char*)Kt + (j*256 + w*64)*16), 16, 0, 0);
    }
    // stage V^T tile [128 d][64 t] via global_load_lds, pre-swizzled source
    #pragma unroll
    for (int j=0;j<4;++j){
      int chunk = j*256 + w*64 + lane;      // 8 chunks/row
      int row = chunk >> 3, cc = chunk & 7;
      int ccs = cc ^ (row & 7);
      const unsigned short* g = vtb + (size_t)row*L_ + t0 + ccs*8;
      __builtin_amdgcn_global_load_lds((gp_t)g,
          (lp_t)((char*)Vt + (j*256 + w*64)*16), 16, 0, 0);
    }
    __syncthreads();

    // scores: S = Q K^T (per wave: 16 q-rows x 64 t-cols)
    f32x4 sc[4];
    #pragma unroll
    for (int nf=0;nf<4;++nf){
      f32x4 a = {0.f,0.f,0.f,0.f};
      #pragma unroll
      for (int ks=0;ks<4;++ks){
        int row = nf*16 + lr;
        int byte = (row*256 + ks*64 + lg*16) ^ ((row & 7) << 4);
        bf16x8 kb = *(const bf16x8*)((const char*)Kt + byte);
        a = __builtin_amdgcn_mfma_f32_16x16x32_bf16(qf[ks], kb, a, 0, 0, 0);
      }
      sc[nf] = a;
    }

    // mask batch index = (b*H + h) % B = h & 1  (reference tiles mask H times on axis 0)
    const float* mb = mask + (size_t)(h & 1)*L_*L_ + (size_t)(POS_ + q0 + w*16)*L_ + t0;
    float sv[4][4];
    float tmax[4] = {-1e30f,-1e30f,-1e30f,-1e30f};
    #pragma unroll
    for (int nf=0;nf<4;++nf)
      #pragma unroll
      for (int i=0;i<4;++i){
        float v = sc[nf][i]*isc + mb[(size_t)(lg*4+i)*L_ + nf*16 + lr];
        sv[nf][i] = v;
        tmax[i] = fmaxf(tmax[i], v);
      }
    #pragma unroll
    for (int i=0;i<4;++i){
      tmax[i] = fmaxf(tmax[i], __shfl_xor(tmax[i], 1));
      tmax[i] = fmaxf(tmax[i], __shfl_xor(tmax[i], 2));
      tmax[i] = fmaxf(tmax[i], __shfl_xor(tmax[i], 4));
      tmax[i] = fmaxf(tmax[i], __shfl_xor(tmax[i], 8));
    }
    float corr[4];
    #pragma unroll
    for (int i=0;i<4;++i){
      float mn = fmaxf(m_i[i], tmax[i]);
      corr[i] = __expf(m_i[i] - mn);
      m_i[i] = mn;
    }
    float rs[4] = {0.f,0.f,0.f,0.f};
    float pp[4][4];
    #pragma unroll
    for (int nf=0;nf<4;++nf)
      #pragma unroll
      for (int i=0;i<4;++i){
        float p = __expf(sv[nf][i] - m_i[i]);
        pp[nf][i] = p;
        rs[i] += p;
      }
    #pragma unroll
    for (int i=0;i<4;++i){
      rs[i] += __shfl_xor(rs[i], 1);
      rs[i] += __shfl_xor(rs[i], 2);
      rs[i] += __shfl_xor(rs[i], 4);
      rs[i] += __shfl_xor(rs[i], 8);
      l_i[i] = l_i[i]*corr[i] + rs[i];
    }
    #pragma unroll
    for (int df=0;df<8;++df)
      #pragma unroll
      for (int i=0;i<4;++i) oacc[df][i] *= corr[i];

    // P -> per-wave LDS (swizzled), then PV MFMAs
    #pragma unroll
    for (int nf=0;nf<4;++nf)
      #pragma unroll
      for (int i=0;i<4;++i){
        int row = lg*4 + i;
        int byte = (row*128 + nf*32 + lr*2) ^ ((row & 7) << 4);
        *(unsigned short*)((char*)(&Pw[w][0]) + byte) = f2bf(pp[nf][i]);
      }
    __asm__ volatile("s_waitcnt lgkmcnt(0)" ::: "memory");
    #pragma unroll
    for (int ks2=0; ks2<2; ++ks2){
      int pbyte = (lr*128 + ks2*64 + lg*16) ^ ((lr & 7) << 4);
      bf16x8 pa = *(const bf16x8*)((const char*)(&Pw[w][0]) + pbyte);
      #pragma unroll
      for (int df=0;df<8;++df){
        int vrow = df*16 + lr;
        int vbyte = (vrow*128 + ks2*64 + lg*16) ^ ((vrow & 7) << 4);
        bf16x8 vb = *(const bf16x8*)((const char*)Vt + vbyte);
        oacc[df] = __builtin_amdgcn_mfma_f32_16x16x32_bf16(pa, vb, oacc[df], 0, 0, 0);
      }
    }
    __syncthreads();
  }
  size_t ob = ((size_t)(b*S_ + q0 + w*16))*HID + h*D_;
  #pragma unroll
  for (int df=0;df<8;++df)
    #pragma unroll
    for (int i=0;i<4;++i){
      float val = oacc[df][i] / l_i[i];
      Ob[ob + (size_t)(lg*4+i)*HID + df*16 + lr] = f2bf(val);
    }
}

extern "C" void kernel_launch(void* const* d_in, const int* in_sizes, int n_in,
                              void* d_out, int out_size, void* d_ws, size_t ws_size,
                              hipStream_t stream){
  const float* x    = (const float*)d_in[0];
  const float* mask = (const float*)d_in[1];
  const float* cosb = (const float*)d_in[2];
  const float* sinb = (const float*)d_in[3];
  const float* kc   = (const float*)d_in[4];
  const float* vc   = (const float*)d_in[5];
  const float* Wq   = (const float*)d_in[8];
  const float* bq   = (const float*)d_in[9];
  const float* Wk   = (const float*)d_in[10];
  const float* bk   = (const float*)d_in[11];
  const float* Wv   = (const float*)d_in[12];
  const float* bv   = (const float*)d_in[13];
  const float* Wo   = (const float*)d_in[14];
  const float* bo   = (const float*)d_in[15];

  float* out  = (float*)d_out;
  float* kout = out + 4194304;
  float* vout = out + 8388608;

  char* ws = (char*)d_ws;
  float*          qkv   = (float*)(ws);                      // 2048*6144*4  = 50331648
  unsigned short* xb    = (unsigned short*)(ws + 50331648);  // 8388608
  unsigned short* Wqkvb = (unsigned short*)(ws + 58720256);  // 25165824
  unsigned short* Wob   = (unsigned short*)(ws + 83886080);  // 8388608
  float*          bqkv  = (float*)(ws + 92274688);           // 24576
  unsigned short* qb    = (unsigned short*)(ws + 92299264);  // 8388608
  unsigned short* kf    = (unsigned short*)(ws + 100687872); // 16777216
  unsigned short* vt    = (unsigned short*)(ws + 117465088); // 16777216 (V^T [b][h][d][t])
  unsigned short* attnb = (unsigned short*)(ws + 134242304); // 8388608

  hipMemcpyAsync(bqkv,        bq, 2048*sizeof(float), hipMemcpyDeviceToDevice, stream);
  hipMemcpyAsync(bqkv + 2048, bk, 2048*sizeof(float), hipMemcpyDeviceToDevice, stream);
  hipMemcpyAsync(bqkv + 4096, bv, 2048*sizeof(float), hipMemcpyDeviceToDevice, stream);

  k_cvt<<<4096, 256, 0, stream>>>(x,  xb, 4194304);
  k_cvt<<<4096, 256, 0, stream>>>(Wq, Wqkvb,            4194304);
  k_cvt<<<4096, 256, 0, stream>>>(Wk, Wqkvb + 4194304,  4194304);
  k_cvt<<<4096, 256, 0, stream>>>(Wv, Wqkvb + 8388608,  4194304);
  k_cvt<<<4096, 256, 0, stream>>>(Wo, Wob, 4194304);
  k_cache<<<4096, 256, 0, stream>>>(kc, kf);

  k_gemm<<<16*48, 256, 0, stream>>>(xb, Wqkvb, bqkv, qkv, 2048, 6144, 2048);
  k_rope<<<8192, 256, 0, stream>>>(qkv, cosb, sinb, kout, vout, qb, kf);
  k_vtrans<<<1024, 256, 0, stream>>>(vc, qkv, vt);
  k_attn<<<512, 256, 0, stream>>>(qb, kf, vt, mask, attnb);
  k_gemm<<<16*16, 256, 0, stream>>>(attnb, Wob, bo, out, 2048, 2048, 2048);

  (void)in_sizes; (void)n_in; (void)out_size; (void)ws_size;
}